// Round 1
// baseline (76.502 us; speedup 1.0000x reference)
//
#include <hip/hip_runtime.h>

#define NBINS 100
#define PWL_VMIN -5.0f
#define PWL_VMAX 5.0f

// ---------------------------------------------------------------------------
// Kernel 1: build lookup tables in workspace.
//   ws[0 .. NBINS]          k_table[i]    = exp(p[i]) + 0.001          (101)
//   ws[NBINS+1 .. 2*NBINS]  delta_bias[j] = b + prefix_cumsum          (100)
// Sequential cumsum on one thread to match jnp.cumsum rounding order.
// ---------------------------------------------------------------------------
__global__ __launch_bounds__(128) void build_tables_kernel(
    const float* __restrict__ p,   // [NBINS+1]
    const float* __restrict__ b,   // [1]
    float* __restrict__ ws)
{
    __shared__ float s_k[NBINS + 1];
    const int t = threadIdx.x;
    if (t <= NBINS) {
        float k = expf(p[t]) + 0.001f;
        s_k[t] = k;
        ws[t]  = k;
    }
    __syncthreads();
    if (t == 0) {
        const float int_length = (PWL_VMAX - PWL_VMIN) / (float)(NBINS - 1);
        const float b0 = b[0];
        float acc = 0.0f;                 // prefix[0] = 0
        ws[NBINS + 1 + 0] = b0;           // delta_bias[0] = b
        for (int i = 1; i < NBINS; ++i) {
            acc += int_length * s_k[i];   // delta_h[i-1] = int_length * k[i]
            ws[NBINS + 1 + i] = b0 + acc; // match reference: b + prefix (b added last)
        }
    }
}

// ---------------------------------------------------------------------------
// Kernel 2: main elementwise PWL. float4 grid-stride, tables staged in LDS.
// index = count of points[j] <= e  (exact vs reference via fixup against the
// actual points array, so linspace ulp differences cannot change the bucket).
// ---------------------------------------------------------------------------
__global__ __launch_bounds__(256) void pwl_kernel(
    const float* __restrict__ eps,     // [N]
    const float* __restrict__ points,  // [NBINS]
    const float* __restrict__ ws,      // tables from kernel 1
    float* __restrict__ out,           // [N]
    int n4)                            // N/4 float4 groups
{
    __shared__ float s_pts[NBINS];
    __shared__ float s_k[NBINS + 1];
    __shared__ float s_db[NBINS];

    const int t = threadIdx.x;
    if (t < NBINS) {
        s_pts[t] = points[t];
        s_db[t]  = ws[NBINS + 1 + t];
    }
    if (t <= NBINS) s_k[t] = ws[t];
    __syncthreads();

    const float inv_step = (float)(NBINS - 1) / (PWL_VMAX - PWL_VMIN);

    const float4* __restrict__ in4  = reinterpret_cast<const float4*>(eps);
    float4* __restrict__       out4 = reinterpret_cast<float4*>(out);

    for (int i = blockIdx.x * blockDim.x + t; i < n4; i += gridDim.x * blockDim.x) {
        float4 e4 = in4[i];
        float ev[4] = {e4.x, e4.y, e4.z, e4.w};
        float r[4];
#pragma unroll
        for (int j = 0; j < 4; ++j) {
            const float e = ev[j];
            // arithmetic guess for index = #(points <= e), then exact fixup
            int idx = (int)floorf((e - PWL_VMIN) * inv_step) + 1;
            idx = max(0, min(idx, NBINS));
            while (idx < NBINS && s_pts[idx] <= e) ++idx;   // converges in <=1 step
            while (idx > 0 && s_pts[idx - 1] > e) --idx;    // converges in <=1 step
            const int si = max(idx - 1, 0);
            r[j] = (e - s_pts[si]) * s_k[idx] + s_db[si];
        }
        float4 o4;
        o4.x = r[0]; o4.y = r[1]; o4.z = r[2]; o4.w = r[3];
        out4[i] = o4;
    }
}

// ---------------------------------------------------------------------------
extern "C" void kernel_launch(void* const* d_in, const int* in_sizes, int n_in,
                              void* d_out, int out_size, void* d_ws, size_t ws_size,
                              hipStream_t stream)
{
    const float* eps    = (const float*)d_in[0];  // [4M, 1]
    const float* p      = (const float*)d_in[1];  // [101]
    const float* b      = (const float*)d_in[2];  // [1]
    const float* points = (const float*)d_in[3];  // [1, 100]
    float* out          = (float*)d_out;          // [4M, 1]
    float* ws           = (float*)d_ws;           // >= 201 floats needed

    build_tables_kernel<<<1, 128, 0, stream>>>(p, b, ws);

    const int n  = out_size;        // 4,000,000 (divisible by 4)
    const int n4 = n / 4;
    const int block = 256;
    int grid = (n4 + block - 1) / block;
    if (grid > 2048) grid = 2048;   // grid-stride the rest
    pwl_kernel<<<grid, block, 0, stream>>>(eps, points, ws, out, n4);

    // handle any non-multiple-of-4 tail (n is 4M, so this is a no-op; kept for safety)
    const int tail = n & 3;
    if (tail) {
        // scalar tail via the same kernel logic is unnecessary complexity here;
        // n is statically 4,000,000 in this problem, so tail == 0.
    }
}